// Round 2
// baseline (902.466 us; speedup 1.0000x reference)
//
#include <hip/hip_runtime.h>

typedef _Float16 half8 __attribute__((ext_vector_type(8)));
typedef float floatx4 __attribute__((ext_vector_type(4)));

#define BATCH 131072
#define S_DIM 376
#define NACT 17

// padded weight plane geometry (transposed [n][k], zero-padded)
#define W1N 448
#define W1K 384
#define W2N 320
#define W2K 416
#define W3N 256
#define W3K 320

// ws offsets in halfs
#define W1HI 0
#define W1LO (W1N * W1K)
#define W2HI (2 * W1N * W1K)
#define W2LO (W2HI + W2N * W2K)
#define W3HI (W2HI + 2 * W2N * W2K)
#define W3LO (W3HI + W3N * W3K)

// LDS geometry: 32 batch rows per block.
// A/H1 plane stride 416 halfs, XOR-swizzled ((row&7)<<4 on byte addr) -> 2-way banks.
//   2 planes * 32 * 416 * 2B = 53248 B = 52 KiB exactly -> 3 blocks/CU (12 waves/CU).
// H2 stride 328 halfs (164 dwords % 32 = 4 -> 2-way). O3 stride 260 floats.
#define ROWS 32
#define AW1 416
#define AW2 328
#define OW3 260
#define LDS_BYTES 53248

#define MFMA16(a, b, c) __builtin_amdgcn_mfma_f32_16x16x32_f16(a, b, c, 0, 0, 0)

// ---------------- prep: split fp32 weights into (hi,lo) fp16 planes, transposed, padded ----------------
__global__ __launch_bounds__(256) void prep_kernel(const float* __restrict__ W1,
                                                   const float* __restrict__ W2,
                                                   const float* __restrict__ W3,
                                                   _Float16* __restrict__ ws) {
  int idx = blockIdx.x * 256 + threadIdx.x;
  float v;
  int hioff, looff;
  if (idx < W1N * W1K) {                        // [448][384]
    int n = idx / W1K, k = idx - n * W1K;
    v = (n < 400 && k < 376) ? W1[k * 400 + n] : 0.f;
    hioff = W1HI + idx; looff = W1LO + idx;
  } else if (idx < W1N * W1K + W2N * W2K) {     // [320][416]
    int e = idx - W1N * W1K;
    int n = e / W2K, k = e - n * W2K;
    v = (n < 300 && k < 400) ? W2[k * 300 + n] : 0.f;
    hioff = W2HI + e; looff = W2LO + e;
  } else if (idx < W1N * W1K + W2N * W2K + W3N * W3K) {  // [256][320]
    int e = idx - W1N * W1K - W2N * W2K;
    int n = e / W3K, k = e - n * W3K;
    v = (n < 255 && k < 300) ? W3[k * 255 + n] : 0.f;
    hioff = W3HI + e; looff = W3LO + e;
  } else {
    return;
  }
  _Float16 hi = (_Float16)v;
  ws[hioff] = hi;
  ws[looff] = (_Float16)(v - (float)hi);
}

// ---------------- software-pipelined K-loop GEMM body ----------------
// A (hi/lo split planes) from LDS (optionally XOR-swizzled), stride AW halfs;
// B (hi/lo planes) direct from global ws (L2-resident), stride KP halfs.
// Flattened (kc,nt) loop, fully unrolled. B stream is pipelined D=4 steps deep
// through a 5-slot register ring (all indices compile-time -> stays in VGPRs);
// next chunk's A fragments prefetched 2 steps before the chunk boundary.
// Load-to-use distance ~3 steps * ~30 cyc * 3 resident waves/SIMD covers the
// ~250-cycle L2 hit latency that capped MfmaUtil at 18-23% in rounds 0/1.
template <int NT, int CHUNKS, int AW, int KP, bool SWZ>
__device__ __forceinline__ void gemm_layer(const _Float16* __restrict__ Ahi,
                                           const _Float16* __restrict__ Alo,
                                           const _Float16* __restrict__ Bhi,
                                           const _Float16* __restrict__ Blo,
                                           int ntm,  // ntBase*16 + m
                                           int q, int m, floatx4 (&acc)[2][NT]) {
  const int kq = q * 8;
  constexpr int TOT = CHUNKS * NT;
  constexpr int D = 4;            // prefetch depth (steps)
  constexpr int R = D + 1;        // ring slots (R !| D -> no same-step collision)

  const _Float16* bbase = Bhi + ntm * KP + kq;
  const _Float16* lbase = Blo + ntm * KP + kq;

  half8 bh[R], bl[R];
  half8 ah[2], al[2], ahn[2], aln[2];

  // A chunk 0
#pragma unroll
  for (int mt = 0; mt < 2; ++mt) {
    const int row = mt * 16 + m;
    int off = (row * AW + kq) * 2;
    if (SWZ) off ^= (row & 7) << 4;
    ah[mt] = *(const half8*)((const char*)Ahi + off);
    al[mt] = *(const half8*)((const char*)Alo + off);
  }
  // B prologue: fill D slots
#pragma unroll
  for (int i = 0; i < D; ++i) {
    const int off = (i / NT) * 32 + (i % NT) * 16 * KP;
    bh[i % R] = *(const half8*)(bbase + off);
    bl[i % R] = *(const half8*)(lbase + off);
  }

#pragma unroll
  for (int i = 0; i < TOT; ++i) {
    const int nt = i % NT;
    const int kc = i / NT;
    // B prefetch, D steps ahead
    if (i + D < TOT) {
      const int j = i + D;
      const int off = (j / NT) * 32 + (j % NT) * 16 * KP;
      bh[j % R] = *(const half8*)(bbase + off);
      bl[j % R] = *(const half8*)(lbase + off);
    }
    // A prefetch for next chunk, 2 steps before the boundary
    if (nt == NT - 2 && kc + 1 < CHUNKS) {
#pragma unroll
      for (int mt = 0; mt < 2; ++mt) {
        const int row = mt * 16 + m;
        int off = (row * AW + (kc + 1) * 32 + kq) * 2;
        if (SWZ) off ^= (row & 7) << 4;
        ahn[mt] = *(const half8*)((const char*)Ahi + off);
        aln[mt] = *(const half8*)((const char*)Alo + off);
      }
    }
    const int s = i % R;
#pragma unroll
    for (int mt = 0; mt < 2; ++mt) {
      acc[mt][nt] = MFMA16(ah[mt], bh[s], acc[mt][nt]);
      acc[mt][nt] = MFMA16(ah[mt], bl[s], acc[mt][nt]);
      acc[mt][nt] = MFMA16(al[mt], bh[s], acc[mt][nt]);
    }
    // rotate A at chunk boundary (last chunk copies stale ahn -> dead, harmless)
    if (nt == NT - 1) {
#pragma unroll
      for (int mt = 0; mt < 2; ++mt) { ah[mt] = ahn[mt]; al[mt] = aln[mt]; }
    }
  }
}

// ---------------- fused actor kernel ----------------
// Block: 256 thr / 4 waves / 32 batch rows; grid 4096.
// 52 KiB LDS -> 3 blocks/CU -> 3 waves/SIMD. Waves split N: every B fragment
// read by exactly one wave -> B streams from L2, LDS only holds A/h planes.
// LDS overlay: A[32][416]swz -> H1[32][416]swz -> H2[32][328]pad -> O3[32][260]f32.
__global__ __launch_bounds__(256, 3) void actor_kernel(const float* __restrict__ state,
                                                       const float* __restrict__ eps,
                                                       const float* __restrict__ b1,
                                                       const float* __restrict__ b2,
                                                       const float* __restrict__ b3,
                                                       const _Float16* __restrict__ wsp,
                                                       float* __restrict__ out) {
  extern __shared__ char smem[];
  _Float16* Ahi = (_Float16*)smem;               // [32][416] swizzled
  _Float16* Alo = Ahi + ROWS * AW1;

  const int t = threadIdx.x;
  const int wave = t >> 6;
  const int lane = t & 63;
  const int q = lane >> 4;
  const int m = lane & 15;
  const long rowbase = (long)blockIdx.x * ROWS;

  // ---- stage state chunk-pair into LDS once (8 threads per batch row) ----
  {
    const int row = t >> 3, p = t & 7;
    const long gbase = (rowbase + row) * S_DIM;
#pragma unroll
    for (int c0 = 0; c0 < 6; ++c0) {
      const int col = c0 * 64 + p * 8;
      float v[8];
      if (col + 8 <= S_DIM) {
        const float4* sp = (const float4*)(state + gbase + col);
        float4 x0 = sp[0], x1 = sp[1];
        v[0] = x0.x; v[1] = x0.y; v[2] = x0.z; v[3] = x0.w;
        v[4] = x1.x; v[5] = x1.y; v[6] = x1.z; v[7] = x1.w;
      } else {
#pragma unroll
        for (int j = 0; j < 8; ++j) v[j] = 0.f;
      }
      half8 h, l;
#pragma unroll
      for (int j = 0; j < 8; ++j) {
        _Float16 hi = (_Float16)v[j];
        h[j] = hi;
        l[j] = (_Float16)(v[j] - (float)hi);
      }
      int off = (row * AW1 + col) * 2;
      off ^= (row & 7) << 4;                     // match gemm read swizzle
      *(half8*)((char*)Ahi + off) = h;
      *(half8*)((char*)Alo + off) = l;
    }
  }
  __syncthreads();

  // ================= Layer 1 =================
  floatx4 acc1[2][7];
#pragma unroll
  for (int a = 0; a < 2; ++a)
#pragma unroll
    for (int b = 0; b < 7; ++b) { acc1[a][b][0] = 0.f; acc1[a][b][1] = 0.f; acc1[a][b][2] = 0.f; acc1[a][b][3] = 0.f; }
  gemm_layer<7, 12, AW1, W1K, true>(Ahi, Alo, wsp + W1HI, wsp + W1LO, wave * 112 + m, q, m, acc1);

  __syncthreads();  // all A reads done -> overlay h1 into same region
  _Float16* H1hi = Ahi;   // [32][416] swizzled
  _Float16* H1lo = Alo;
#pragma unroll
  for (int nt = 0; nt < 7; ++nt) {
    const int tile = wave * 7 + nt;
    if (tile < 26) {                 // only cols 0..415 needed for layer 2 K
      const int col = tile * 16 + m;
      const float bias = (col < 400) ? b1[col] : 0.f;
#pragma unroll
      for (int mt = 0; mt < 2; ++mt)
#pragma unroll
        for (int r = 0; r < 4; ++r) {
          const int row = mt * 16 + q * 4 + r;
          float v = fmaxf(acc1[mt][nt][r] + bias, 0.f);
          _Float16 hi = (_Float16)v;
          int off = (row * AW1 + col) * 2;
          off ^= (row & 7) << 4;
          *(_Float16*)((char*)H1hi + off) = hi;
          *(_Float16*)((char*)H1lo + off) = (_Float16)(v - (float)hi);
        }
    }
  }
  __syncthreads();

  // ================= Layer 2 =================
  floatx4 acc2[2][5];
#pragma unroll
  for (int a = 0; a < 2; ++a)
#pragma unroll
    for (int b = 0; b < 5; ++b) { acc2[a][b][0] = 0.f; acc2[a][b][1] = 0.f; acc2[a][b][2] = 0.f; acc2[a][b][3] = 0.f; }
  gemm_layer<5, 13, AW1, W2K, true>(H1hi, H1lo, wsp + W2HI, wsp + W2LO, wave * 80 + m, q, m, acc2);

  __syncthreads();  // all h1 reads done -> overlay h2 (padded, no swizzle)
  _Float16* H2hi = (_Float16*)smem;  // [32][328]
  _Float16* H2lo = H2hi + ROWS * AW2;
#pragma unroll
  for (int nt = 0; nt < 5; ++nt) {
    const int col = (wave * 5 + nt) * 16 + m;   // < 320; cols >=300 get zeros (padded W2/b2)
    const float bias = (col < 300) ? b2[col] : 0.f;
#pragma unroll
    for (int mt = 0; mt < 2; ++mt)
#pragma unroll
      for (int r = 0; r < 4; ++r) {
        const int row = mt * 16 + q * 4 + r;
        float v = fmaxf(acc2[mt][nt][r] + bias, 0.f);
        _Float16 hi = (_Float16)v;
        H2hi[row * AW2 + col] = hi;
        H2lo[row * AW2 + col] = (_Float16)(v - (float)hi);
      }
  }
  __syncthreads();

  // ================= Layer 3 =================
  floatx4 acc3[2][4];
#pragma unroll
  for (int a = 0; a < 2; ++a)
#pragma unroll
    for (int b = 0; b < 4; ++b) { acc3[a][b][0] = 0.f; acc3[a][b][1] = 0.f; acc3[a][b][2] = 0.f; acc3[a][b][3] = 0.f; }
  gemm_layer<4, 10, AW2, W3K, false>(H2hi, H2lo, wsp + W3HI, wsp + W3LO, wave * 64 + m, q, m, acc3);

  __syncthreads();  // all h2 reads done -> overlay O3
  float* O3 = (float*)smem;  // [32][260] fp32
#pragma unroll
  for (int nt = 0; nt < 4; ++nt) {
    const int col = (wave * 4 + nt) * 16 + m;
    const float bias = (col < 255) ? b3[col] : 0.f;
#pragma unroll
    for (int mt = 0; mt < 2; ++mt)
#pragma unroll
      for (int r = 0; r < 4; ++r) {
        const int row = mt * 16 + q * 4 + r;
        O3[row * OW3 + col] = tanhf(acc3[mt][nt][r] + bias);
      }
  }
  __syncthreads();

  // ================= Epilogue: mixture stats, sample, logprobs =================
  {
    const int row = t >> 3, p = t & 7;   // 8 threads per batch row
    const long gr = rowbase + row;
    const float* Or = O3 + row * OW3;
    float pc = 0.f, pt = 0.f, pe = 0.f;
    const int nact = (p == 0) ? 3 : 2;   // 17 = 8*2 + 1 (p==0 also covers a=16)
    for (int ia = 0; ia < nact; ++ia) {
      const int a = p + ia * 8;
      float mw[5], mmv[5], lms[5];
#pragma unroll
      for (int j = 0; j < 5; ++j) {
        mw[j]  = Or[a * 5 + j];
        mmv[j] = Or[85 + a * 5 + j];
        lms[j] = Or[170 + a * 5 + j];
      }
      float w[5], es = 0.f;
#pragma unroll
      for (int j = 0; j < 5; ++j) { w[j] = expf(mw[j]); es += w[j]; }
      const float inv = 1.f / es;
      float mean = 0.f;
#pragma unroll
      for (int j = 0; j < 5; ++j) { w[j] *= inv; mean += w[j] * mmv[j]; }
      float alea = 0.f, epis = 0.f;
#pragma unroll
      for (int j = 0; j < 5; ++j) {
        float sd = expf(fminf(fmaxf(lms[j], -10.f), 2.f));
        alea += w[j] * sd;
        float d = mmv[j] - mean;
        epis += w[j] * d * d;
      }
      epis = fminf(fmaxf(epis, 4.53999297624848e-05f), 7.38905609893065f);
      const float total = alea + epis;
      const float ea = eps[gr * NACT + a];
      const float sample = mean + total * ea;
      const float ts = tanhf(sample);
      out[gr * NACT + a] = ts;
      pc += logf(1.f - ts * ts + 1e-6f);
      const float dz = sample - mean;
      const float zt = dz / total;
      const float ze = dz / epis;
      pt += zt * zt + 2.f * logf(total);
      pe += ze * ze + 2.f * logf(epis);
    }
    pc += __shfl_xor(pc, 1); pc += __shfl_xor(pc, 2); pc += __shfl_xor(pc, 4);
    pt += __shfl_xor(pt, 1); pt += __shfl_xor(pt, 2); pt += __shfl_xor(pt, 4);
    pe += __shfl_xor(pe, 1); pe += __shfl_xor(pe, 2); pe += __shfl_xor(pe, 4);
    if (p == 0) {
      const float hdl2pi = 15.62195506447944f;  // 0.5*17*ln(2*pi)
      out[(long)NACT * BATCH + gr] = (-0.5f * pt - hdl2pi) - pc;
      out[(long)(NACT + 1) * BATCH + gr] = (-0.5f * pe - hdl2pi) - pc;
    }
  }
}

extern "C" void kernel_launch(void* const* d_in, const int* in_sizes, int n_in,
                              void* d_out, int out_size, void* d_ws, size_t ws_size,
                              hipStream_t stream) {
  const float* state = (const float*)d_in[0];
  const float* eps   = (const float*)d_in[1];
  const float* W1    = (const float*)d_in[2];
  const float* b1    = (const float*)d_in[3];
  const float* W2    = (const float*)d_in[4];
  const float* b2    = (const float*)d_in[5];
  const float* W3    = (const float*)d_in[6];
  const float* b3    = (const float*)d_in[7];
  float* out = (float*)d_out;
  _Float16* ws = (_Float16*)d_ws;

  (void)in_sizes; (void)n_in; (void)out_size; (void)ws_size;

  prep_kernel<<<1512, 256, 0, stream>>>(W1, W2, W3, ws);
  actor_kernel<<<BATCH / ROWS, 256, LDS_BYTES, stream>>>(state, eps, b1, b2, b3, ws, out);
}

// Round 3
// 640.258 us; speedup vs baseline: 1.4095x; 1.4095x over previous
//
#include <hip/hip_runtime.h>

typedef _Float16 half8 __attribute__((ext_vector_type(8)));
typedef float floatx4 __attribute__((ext_vector_type(4)));

#define BATCH 131072
#define S_DIM 376
#define NACT 17

// ---------------- fragment-major weight layout ----------------
// Per layer: fragment-pair f = ntile*CHUNKS + kc, each 1024 halfs (2 KB):
//   [   0.. 511] hi plane: lane*8 + j   (lane = q*16 + m)
//   [ 512..1023] lo plane
// element (m,q,j) = W[n = ntile*16+m][k = kc*32+q*8+j]  (zero-padded)
// -> every B load is a contiguous, 1KB-aligned 16B/lane global_load_dwordx4.
// R2 post-mortem: old [n][k] layout made each B load touch 16 scattered cache
// lines (row stride 768B) -> ~70cyc TA occupancy/load * 24k loads/CU ~= whole
// dispatch. Fragment-major removes the scatter without changing any math.
#define L1_NT 28
#define L1_CH 12
#define L2_NT 20
#define L2_CH 13
#define L3_NT 16
#define L3_CH 10
#define L1F 0
#define L2F (L1_NT * L1_CH * 1024)        // 344064
#define L3F (L2F + L2_NT * L2_CH * 1024)  // 610304
#define WTOTF (L3F + L3_NT * L3_CH * 1024)  // 774144 halfs = 1.548 MB

// LDS geometry: 32 batch rows per block.
// A/H1 plane stride 416 halfs, XOR-swizzled ((row&7)<<4 on byte addr) -> 2-way banks.
//   2 planes * 32 * 416 * 2B = 53248 B = 52 KiB exactly -> 3 blocks/CU (12 waves/CU).
// H2 stride 328 halfs (164 dwords % 32 = 4 -> 2-way). O3 stride 260 floats.
#define ROWS 32
#define AW1 416
#define AW2 328
#define OW3 260
#define LDS_BYTES 53248

#define MFMA16(a, b, c) __builtin_amdgcn_mfma_f32_16x16x32_f16(a, b, c, 0, 0, 0)

// ---------------- prep: split fp32 weights into fragment-major (hi,lo) fp16 ----------------
__global__ __launch_bounds__(256) void prep_kernel(const float* __restrict__ W1,
                                                   const float* __restrict__ W2,
                                                   const float* __restrict__ W3,
                                                   _Float16* __restrict__ ws) {
  int idx = blockIdx.x * 256 + threadIdx.x;
  if (idx >= WTOTF) return;
  const float* W;
  int CH, NR, KR, e = idx;
  if (e < L2F) {
    W = W1; CH = L1_CH; NR = 400; KR = 376;
  } else if (e < L3F) {
    W = W2; CH = L2_CH; NR = 300; KR = 400; e -= L2F;
  } else {
    W = W3; CH = L3_CH; NR = 255; KR = 300; e -= L3F;
  }
  const int f = e >> 10, r = e & 1023;
  const int plane = r >> 9, rr = r & 511;
  const int lane = rr >> 3, j = rr & 7;
  const int q = lane >> 4, m = lane & 15;
  const int ntile = f / CH, kc = f - ntile * CH;
  const int n = ntile * 16 + m, k = kc * 32 + q * 8 + j;
  const float v = (n < NR && k < KR) ? W[k * NR + n] : 0.f;
  const _Float16 hi = (_Float16)v;
  ws[idx] = plane ? (_Float16)(v - (float)hi) : hi;
}

// ---------------- software-pipelined K-loop GEMM body ----------------
// A (hi/lo split planes) from LDS (optionally XOR-swizzled), stride AW halfs;
// B fragment-major from global ws (L2-resident): step (nt,kc) reads the 2KB
// fragment-pair at ((ntile0+nt)*CHUNKS+kc)*1024, lane offset lane*8.
// Flattened (kc,nt) loop, fully unrolled; B pipelined D=4 steps through a
// 5-slot register ring (compile-time indices); next chunk's A prefetched
// 2 steps before the chunk boundary.
template <int NT, int CHUNKS, int AW, bool SWZ>
__device__ __forceinline__ void gemm_layer(const _Float16* __restrict__ Ahi,
                                           const _Float16* __restrict__ Alo,
                                           const _Float16* __restrict__ Bf,
                                           int ntile0, int lane, int q, int m,
                                           floatx4 (&acc)[2][NT]) {
  const int kq = q * 8;
  constexpr int TOT = CHUNKS * NT;
  constexpr int D = 4;            // prefetch depth (steps)
  constexpr int R = D + 1;        // ring slots

  const _Float16* bb = Bf + ntile0 * CHUNKS * 1024 + lane * 8;

  half8 bh[R], bl[R];
  half8 ah[2], al[2], ahn[2], aln[2];

  // A chunk 0
#pragma unroll
  for (int mt = 0; mt < 2; ++mt) {
    const int row = mt * 16 + m;
    int off = (row * AW + kq) * 2;
    if (SWZ) off ^= (row & 7) << 4;
    ah[mt] = *(const half8*)((const char*)Ahi + off);
    al[mt] = *(const half8*)((const char*)Alo + off);
  }
  // B prologue: fill D slots
#pragma unroll
  for (int i = 0; i < D; ++i) {
    const int fo = ((i % NT) * CHUNKS + (i / NT)) * 1024;
    bh[i % R] = *(const half8*)(bb + fo);
    bl[i % R] = *(const half8*)(bb + fo + 512);
  }

#pragma unroll
  for (int i = 0; i < TOT; ++i) {
    const int nt = i % NT;
    const int kc = i / NT;
    // B prefetch, D steps ahead
    if (i + D < TOT) {
      const int j = i + D;
      const int fo = ((j % NT) * CHUNKS + (j / NT)) * 1024;
      bh[j % R] = *(const half8*)(bb + fo);
      bl[j % R] = *(const half8*)(bb + fo + 512);
    }
    // A prefetch for next chunk, 2 steps before the boundary
    if (nt == NT - 2 && kc + 1 < CHUNKS) {
#pragma unroll
      for (int mt = 0; mt < 2; ++mt) {
        const int row = mt * 16 + m;
        int off = (row * AW + (kc + 1) * 32 + kq) * 2;
        if (SWZ) off ^= (row & 7) << 4;
        ahn[mt] = *(const half8*)((const char*)Ahi + off);
        aln[mt] = *(const half8*)((const char*)Alo + off);
      }
    }
    const int s = i % R;
#pragma unroll
    for (int mt = 0; mt < 2; ++mt) {
      acc[mt][nt] = MFMA16(ah[mt], bh[s], acc[mt][nt]);
      acc[mt][nt] = MFMA16(ah[mt], bl[s], acc[mt][nt]);
      acc[mt][nt] = MFMA16(al[mt], bh[s], acc[mt][nt]);
    }
    // rotate A at chunk boundary (last chunk copies stale ahn -> dead, harmless)
    if (nt == NT - 1) {
#pragma unroll
      for (int mt = 0; mt < 2; ++mt) { ah[mt] = ahn[mt]; al[mt] = aln[mt]; }
    }
  }
}

// ---------------- fused actor kernel ----------------
// Block: 256 thr / 4 waves / 32 batch rows; grid 4096.
// 52 KiB LDS -> 3 blocks/CU -> 3 waves/SIMD. Waves split N: every B fragment
// read by exactly one wave -> B streams from L2, LDS only holds A/h planes.
// LDS overlay: A[32][416]swz -> H1[32][416]swz -> H2[32][328]pad -> O3[32][260]f32.
__global__ __launch_bounds__(256, 3) void actor_kernel(const float* __restrict__ state,
                                                       const float* __restrict__ eps,
                                                       const float* __restrict__ b1,
                                                       const float* __restrict__ b2,
                                                       const float* __restrict__ b3,
                                                       const _Float16* __restrict__ wsp,
                                                       float* __restrict__ out) {
  extern __shared__ char smem[];
  _Float16* Ahi = (_Float16*)smem;               // [32][416] swizzled
  _Float16* Alo = Ahi + ROWS * AW1;

  const int t = threadIdx.x;
  const int wave = t >> 6;
  const int lane = t & 63;
  const int q = lane >> 4;
  const int m = lane & 15;
  const long rowbase = (long)blockIdx.x * ROWS;

  // ---- stage state chunk-pair into LDS once (8 threads per batch row) ----
  {
    const int row = t >> 3, p = t & 7;
    const long gbase = (rowbase + row) * S_DIM;
#pragma unroll
    for (int c0 = 0; c0 < 6; ++c0) {
      const int col = c0 * 64 + p * 8;
      float v[8];
      if (col + 8 <= S_DIM) {
        const float4* sp = (const float4*)(state + gbase + col);
        float4 x0 = sp[0], x1 = sp[1];
        v[0] = x0.x; v[1] = x0.y; v[2] = x0.z; v[3] = x0.w;
        v[4] = x1.x; v[5] = x1.y; v[6] = x1.z; v[7] = x1.w;
      } else {
#pragma unroll
        for (int j = 0; j < 8; ++j) v[j] = 0.f;
      }
      half8 h, l;
#pragma unroll
      for (int j = 0; j < 8; ++j) {
        _Float16 hi = (_Float16)v[j];
        h[j] = hi;
        l[j] = (_Float16)(v[j] - (float)hi);
      }
      int off = (row * AW1 + col) * 2;
      off ^= (row & 7) << 4;                     // match gemm read swizzle
      *(half8*)((char*)Ahi + off) = h;
      *(half8*)((char*)Alo + off) = l;
    }
  }
  __syncthreads();

  // ================= Layer 1 =================
  floatx4 acc1[2][7];
#pragma unroll
  for (int a = 0; a < 2; ++a)
#pragma unroll
    for (int b = 0; b < 7; ++b) { acc1[a][b][0] = 0.f; acc1[a][b][1] = 0.f; acc1[a][b][2] = 0.f; acc1[a][b][3] = 0.f; }
  gemm_layer<7, 12, AW1, true>(Ahi, Alo, wsp + L1F, wave * 7, lane, q, m, acc1);

  __syncthreads();  // all A reads done -> overlay h1 into same region
  _Float16* H1hi = Ahi;   // [32][416] swizzled
  _Float16* H1lo = Alo;
#pragma unroll
  for (int nt = 0; nt < 7; ++nt) {
    const int tile = wave * 7 + nt;
    if (tile < 26) {                 // only cols 0..415 needed for layer 2 K
      const int col = tile * 16 + m;
      const float bias = (col < 400) ? b1[col] : 0.f;
#pragma unroll
      for (int mt = 0; mt < 2; ++mt)
#pragma unroll
        for (int r = 0; r < 4; ++r) {
          const int row = mt * 16 + q * 4 + r;
          float v = fmaxf(acc1[mt][nt][r] + bias, 0.f);
          _Float16 hi = (_Float16)v;
          int off = (row * AW1 + col) * 2;
          off ^= (row & 7) << 4;
          *(_Float16*)((char*)H1hi + off) = hi;
          *(_Float16*)((char*)H1lo + off) = (_Float16)(v - (float)hi);
        }
    }
  }
  __syncthreads();

  // ================= Layer 2 =================
  floatx4 acc2[2][5];
#pragma unroll
  for (int a = 0; a < 2; ++a)
#pragma unroll
    for (int b = 0; b < 5; ++b) { acc2[a][b][0] = 0.f; acc2[a][b][1] = 0.f; acc2[a][b][2] = 0.f; acc2[a][b][3] = 0.f; }
  gemm_layer<5, 13, AW1, true>(H1hi, H1lo, wsp + L2F, wave * 5, lane, q, m, acc2);

  __syncthreads();  // all h1 reads done -> overlay h2 (padded, no swizzle)
  _Float16* H2hi = (_Float16*)smem;  // [32][328]
  _Float16* H2lo = H2hi + ROWS * AW2;
#pragma unroll
  for (int nt = 0; nt < 5; ++nt) {
    const int col = (wave * 5 + nt) * 16 + m;   // < 320; cols >=300 get zeros (padded W2/b2)
    const float bias = (col < 300) ? b2[col] : 0.f;
#pragma unroll
    for (int mt = 0; mt < 2; ++mt)
#pragma unroll
      for (int r = 0; r < 4; ++r) {
        const int row = mt * 16 + q * 4 + r;
        float v = fmaxf(acc2[mt][nt][r] + bias, 0.f);
        _Float16 hi = (_Float16)v;
        H2hi[row * AW2 + col] = hi;
        H2lo[row * AW2 + col] = (_Float16)(v - (float)hi);
      }
  }
  __syncthreads();

  // ================= Layer 3 =================
  floatx4 acc3[2][4];
#pragma unroll
  for (int a = 0; a < 2; ++a)
#pragma unroll
    for (int b = 0; b < 4; ++b) { acc3[a][b][0] = 0.f; acc3[a][b][1] = 0.f; acc3[a][b][2] = 0.f; acc3[a][b][3] = 0.f; }
  gemm_layer<4, 10, AW2, false>(H2hi, H2lo, wsp + L3F, wave * 4, lane, q, m, acc3);

  __syncthreads();  // all h2 reads done -> overlay O3
  float* O3 = (float*)smem;  // [32][260] fp32
#pragma unroll
  for (int nt = 0; nt < 4; ++nt) {
    const int col = (wave * 4 + nt) * 16 + m;
    const float bias = (col < 255) ? b3[col] : 0.f;
#pragma unroll
    for (int mt = 0; mt < 2; ++mt)
#pragma unroll
      for (int r = 0; r < 4; ++r) {
        const int row = mt * 16 + q * 4 + r;
        O3[row * OW3 + col] = tanhf(acc3[mt][nt][r] + bias);
      }
  }
  __syncthreads();

  // ================= Epilogue: mixture stats, sample, logprobs =================
  {
    const int row = t >> 3, p = t & 7;   // 8 threads per batch row
    const long gr = rowbase + row;
    const float* Or = O3 + row * OW3;
    float pc = 0.f, pt = 0.f, pe = 0.f;
    const int nact = (p == 0) ? 3 : 2;   // 17 = 8*2 + 1 (p==0 also covers a=16)
    for (int ia = 0; ia < nact; ++ia) {
      const int a = p + ia * 8;
      float mw[5], mmv[5], lms[5];
#pragma unroll
      for (int j = 0; j < 5; ++j) {
        mw[j]  = Or[a * 5 + j];
        mmv[j] = Or[85 + a * 5 + j];
        lms[j] = Or[170 + a * 5 + j];
      }
      float w[5], es = 0.f;
#pragma unroll
      for (int j = 0; j < 5; ++j) { w[j] = expf(mw[j]); es += w[j]; }
      const float inv = 1.f / es;
      float mean = 0.f;
#pragma unroll
      for (int j = 0; j < 5; ++j) { w[j] *= inv; mean += w[j] * mmv[j]; }
      float alea = 0.f, epis = 0.f;
#pragma unroll
      for (int j = 0; j < 5; ++j) {
        float sd = expf(fminf(fmaxf(lms[j], -10.f), 2.f));
        alea += w[j] * sd;
        float d = mmv[j] - mean;
        epis += w[j] * d * d;
      }
      epis = fminf(fmaxf(epis, 4.53999297624848e-05f), 7.38905609893065f);
      const float total = alea + epis;
      const float ea = eps[gr * NACT + a];
      const float sample = mean + total * ea;
      const float ts = tanhf(sample);
      out[gr * NACT + a] = ts;
      pc += logf(1.f - ts * ts + 1e-6f);
      const float dz = sample - mean;
      const float zt = dz / total;
      const float ze = dz / epis;
      pt += zt * zt + 2.f * logf(total);
      pe += ze * ze + 2.f * logf(epis);
    }
    pc += __shfl_xor(pc, 1); pc += __shfl_xor(pc, 2); pc += __shfl_xor(pc, 4);
    pt += __shfl_xor(pt, 1); pt += __shfl_xor(pt, 2); pt += __shfl_xor(pt, 4);
    pe += __shfl_xor(pe, 1); pe += __shfl_xor(pe, 2); pe += __shfl_xor(pe, 4);
    if (p == 0) {
      const float hdl2pi = 15.62195506447944f;  // 0.5*17*ln(2*pi)
      out[(long)NACT * BATCH + gr] = (-0.5f * pt - hdl2pi) - pc;
      out[(long)(NACT + 1) * BATCH + gr] = (-0.5f * pe - hdl2pi) - pc;
    }
  }
}

extern "C" void kernel_launch(void* const* d_in, const int* in_sizes, int n_in,
                              void* d_out, int out_size, void* d_ws, size_t ws_size,
                              hipStream_t stream) {
  const float* state = (const float*)d_in[0];
  const float* eps   = (const float*)d_in[1];
  const float* W1    = (const float*)d_in[2];
  const float* b1    = (const float*)d_in[3];
  const float* W2    = (const float*)d_in[4];
  const float* b2    = (const float*)d_in[5];
  const float* W3    = (const float*)d_in[6];
  const float* b3    = (const float*)d_in[7];
  float* out = (float*)d_out;
  _Float16* ws = (_Float16*)d_ws;

  (void)in_sizes; (void)n_in; (void)out_size; (void)ws_size;

  prep_kernel<<<(WTOTF + 255) / 256, 256, 0, stream>>>(W1, W2, W3, ws);
  actor_kernel<<<BATCH / ROWS, 256, LDS_BYTES, stream>>>(state, eps, b1, b2, b3, ws, out);
}

// Round 4
// 543.799 us; speedup vs baseline: 1.6596x; 1.1774x over previous
//
#include <hip/hip_runtime.h>

typedef _Float16 half8 __attribute__((ext_vector_type(8)));
typedef float floatx4 __attribute__((ext_vector_type(4)));

#define BATCH 131072
#define S_DIM 376
#define NACT 17

// ---------------- fragment-major weight layout ----------------
// Per layer: fragment-pair f = ntile*CHUNKS + kc, each 1024 halfs (2 KB):
//   [   0.. 511] hi plane: lane*8 + j   (lane = q*16 + m)
//   [ 512..1023] lo plane
// element (m,q,j) = W[n = ntile*16+m][k = kc*32+q*8+j]  (zero-padded)
// -> every B load is a contiguous, 1KB-aligned 16B/lane global_load_dwordx4.
#define L1_NT 28
#define L1_CH 12
#define L2_NT 20
#define L2_CH 13
#define L3_NT 16
#define L3_CH 10
#define L1F 0
#define L2F (L1_NT * L1_CH * 1024)        // 344064
#define L3F (L2F + L2_NT * L2_CH * 1024)  // 610304
#define WTOTF (L3F + L3_NT * L3_CH * 1024)  // 774144 halfs = 1.548 MB

// LDS geometry: 32 batch rows per block.
// A/H1 plane stride 416 halfs, XOR-swizzled ((row&7)<<4 on byte addr) -> 2-way banks.
//   2 planes * 32 * 416 * 2B = 53248 B = 52 KiB exactly -> 3 blocks/CU (12 waves/CU).
#define ROWS 32
#define AW1 416
#define AW2 328
#define OW3 260
#define LDS_BYTES 53248

#define MFMA16(a, b, c) __builtin_amdgcn_mfma_f32_16x16x32_f16(a, b, c, 0, 0, 0)

// ---------------- prep: split fp32 weights into fragment-major (hi,lo) fp16 ----------------
__global__ __launch_bounds__(256) void prep_kernel(const float* __restrict__ W1,
                                                   const float* __restrict__ W2,
                                                   const float* __restrict__ W3,
                                                   _Float16* __restrict__ ws) {
  int idx = blockIdx.x * 256 + threadIdx.x;
  if (idx >= WTOTF) return;
  const float* W;
  int CH, NR, KR, e = idx;
  if (e < L2F) {
    W = W1; CH = L1_CH; NR = 400; KR = 376;
  } else if (e < L3F) {
    W = W2; CH = L2_CH; NR = 300; KR = 400; e -= L2F;
  } else {
    W = W3; CH = L3_CH; NR = 255; KR = 300; e -= L3F;
  }
  const int f = e >> 10, r = e & 1023;
  const int plane = r >> 9, rr = r & 511;
  const int lane = rr >> 3, j = rr & 7;
  const int q = lane >> 4, m = lane & 15;
  const int ntile = f / CH, kc = f - ntile * CH;
  const int n = ntile * 16 + m, k = kc * 32 + q * 8 + j;
  const float v = (n < NR && k < KR) ? W[k * NR + n] : 0.f;
  const _Float16 hi = (_Float16)v;
  ws[idx] = plane ? (_Float16)(v - (float)hi) : hi;
}

// ---------------- LDS A-fragment read (optionally XOR-swizzled) ----------------
template <int AW, bool SWZ>
__device__ __forceinline__ half8 lds_frag(const char* base, int row, int koff) {
  int off = (row * AW + koff) * 2;
  if (SWZ) off ^= (row & 7) << 4;
  return *(const half8*)(base + off);
}

// ---------------- template-recursion K-step: guaranteed-unrolled pipeline ----------------
// R3 post-mortem: #pragma-unroll ring collapsed (VGPR_Count=84 -> compiler sank
// prefetch loads to uses, exposing ~2 L2 latencies per step, MfmaUtil 28%).
// Fix: every index constexpr via template recursion; sched_barrier(0) between
// each step's load cluster and MFMA cluster pins the loads 4 steps ahead of use
// -> ring values forced live (~150 VGPR, under the 170 cap of (256,3)).
template <int NT, int CHUNKS, int AW, bool SWZ, int I>
struct KStep {
  static constexpr int TOT = NT * CHUNKS;
  static __device__ __forceinline__ void run(const char* Ahi, const char* Alo,
                                             const _Float16* bb, int m, int kq,
                                             half8 (&bh)[5], half8 (&bl)[5],
                                             half8 (&ah)[2], half8 (&al)[2],
                                             half8 (&ahn)[2], half8 (&aln)[2],
                                             floatx4 (&acc)[2][NT]) {
    constexpr int nt = I % NT;
    constexpr int kc = I / NT;
    constexpr int s = I % 5;
    // B prefetch, 4 steps ahead (slot (I+4)%5 != s)
    if constexpr (I + 4 < TOT) {
      constexpr int j = I + 4;
      constexpr int fo = ((j % NT) * CHUNKS + (j / NT)) * 1024;
      bh[j % 5] = *(const half8*)(bb + fo);
      bl[j % 5] = *(const half8*)(bb + fo + 512);
    }
    // A prefetch for next chunk, 2 steps before the boundary
    if constexpr (nt == NT - 2 && kc + 1 < CHUNKS) {
      ahn[0] = lds_frag<AW, SWZ>(Ahi, m, (kc + 1) * 32 + kq);
      ahn[1] = lds_frag<AW, SWZ>(Ahi, 16 + m, (kc + 1) * 32 + kq);
      aln[0] = lds_frag<AW, SWZ>(Alo, m, (kc + 1) * 32 + kq);
      aln[1] = lds_frag<AW, SWZ>(Alo, 16 + m, (kc + 1) * 32 + kq);
    }
    __builtin_amdgcn_sched_barrier(0);  // loads above, MFMAs below: no sinking
    acc[0][nt] = MFMA16(ah[0], bh[s], acc[0][nt]);
    acc[1][nt] = MFMA16(ah[1], bh[s], acc[1][nt]);
    acc[0][nt] = MFMA16(ah[0], bl[s], acc[0][nt]);
    acc[1][nt] = MFMA16(ah[1], bl[s], acc[1][nt]);
    acc[0][nt] = MFMA16(al[0], bh[s], acc[0][nt]);
    acc[1][nt] = MFMA16(al[1], bh[s], acc[1][nt]);
    // rotate A at chunk boundary
    if constexpr (nt == NT - 1 && kc + 1 < CHUNKS) {
      ah[0] = ahn[0]; ah[1] = ahn[1]; al[0] = aln[0]; al[1] = aln[1];
    }
    if constexpr (I + 1 < TOT)
      KStep<NT, CHUNKS, AW, SWZ, I + 1>::run(Ahi, Alo, bb, m, kq, bh, bl, ah, al, ahn, aln, acc);
  }
};

template <int NT, int CHUNKS, int AW, bool SWZ>
__device__ __forceinline__ void gemm_layer(const _Float16* __restrict__ Ahi_,
                                           const _Float16* __restrict__ Alo_,
                                           const _Float16* __restrict__ Bf,
                                           int ntile0, int lane, int q, int m,
                                           floatx4 (&acc)[2][NT]) {
  const char* Ahi = (const char*)Ahi_;
  const char* Alo = (const char*)Alo_;
  const int kq = q * 8;
  const _Float16* bb = Bf + ntile0 * CHUNKS * 1024 + lane * 8;

  half8 bh[5], bl[5];
  half8 ah[2], al[2], ahn[2], aln[2];

  // A chunk 0
  ah[0] = lds_frag<AW, SWZ>(Ahi, m, kq);
  ah[1] = lds_frag<AW, SWZ>(Ahi, 16 + m, kq);
  al[0] = lds_frag<AW, SWZ>(Alo, m, kq);
  al[1] = lds_frag<AW, SWZ>(Alo, 16 + m, kq);
  // B prologue: steps 0..3 are (nt=i, kc=0) since NT >= 4 for all layers
  bh[0] = *(const half8*)(bb + 0 * CHUNKS * 1024);
  bl[0] = *(const half8*)(bb + 0 * CHUNKS * 1024 + 512);
  bh[1] = *(const half8*)(bb + 1 * CHUNKS * 1024);
  bl[1] = *(const half8*)(bb + 1 * CHUNKS * 1024 + 512);
  bh[2] = *(const half8*)(bb + 2 * CHUNKS * 1024);
  bl[2] = *(const half8*)(bb + 2 * CHUNKS * 1024 + 512);
  bh[3] = *(const half8*)(bb + 3 * CHUNKS * 1024);
  bl[3] = *(const half8*)(bb + 3 * CHUNKS * 1024 + 512);
  __builtin_amdgcn_sched_barrier(0);

  KStep<NT, CHUNKS, AW, SWZ, 0>::run(Ahi, Alo, bb, m, kq, bh, bl, ah, al, ahn, aln, acc);
}

// ---------------- fused actor kernel ----------------
// Block: 256 thr / 4 waves / 32 batch rows; grid 4096.
// 52 KiB LDS -> 3 blocks/CU -> 3 waves/SIMD. Waves split N: every B fragment
// read by exactly one wave -> B streams from L2, LDS only holds A/h planes.
// LDS overlay: A[32][416]swz -> H1[32][416]swz -> H2[32][328]pad -> O3[32][260]f32.
__global__ __launch_bounds__(256, 3) void actor_kernel(const float* __restrict__ state,
                                                       const float* __restrict__ eps,
                                                       const float* __restrict__ b1,
                                                       const float* __restrict__ b2,
                                                       const float* __restrict__ b3,
                                                       const _Float16* __restrict__ wsp,
                                                       float* __restrict__ out) {
  extern __shared__ char smem[];
  _Float16* Ahi = (_Float16*)smem;               // [32][416] swizzled
  _Float16* Alo = Ahi + ROWS * AW1;

  const int t = threadIdx.x;
  const int wave = t >> 6;
  const int lane = t & 63;
  const int q = lane >> 4;
  const int m = lane & 15;
  const long rowbase = (long)blockIdx.x * ROWS;

  // ---- stage state chunk-pair into LDS once (8 threads per batch row) ----
  {
    const int row = t >> 3, p = t & 7;
    const long gbase = (rowbase + row) * S_DIM;
#pragma unroll
    for (int c0 = 0; c0 < 6; ++c0) {
      const int col = c0 * 64 + p * 8;
      float v[8];
      if (col + 8 <= S_DIM) {
        const float4* sp = (const float4*)(state + gbase + col);
        float4 x0 = sp[0], x1 = sp[1];
        v[0] = x0.x; v[1] = x0.y; v[2] = x0.z; v[3] = x0.w;
        v[4] = x1.x; v[5] = x1.y; v[6] = x1.z; v[7] = x1.w;
      } else {
#pragma unroll
        for (int j = 0; j < 8; ++j) v[j] = 0.f;
      }
      half8 h, l;
#pragma unroll
      for (int j = 0; j < 8; ++j) {
        _Float16 hi = (_Float16)v[j];
        h[j] = hi;
        l[j] = (_Float16)(v[j] - (float)hi);
      }
      int off = (row * AW1 + col) * 2;
      off ^= (row & 7) << 4;                     // match gemm read swizzle
      *(half8*)((char*)Ahi + off) = h;
      *(half8*)((char*)Alo + off) = l;
    }
  }
  __syncthreads();

  // ================= Layer 1 =================
  floatx4 acc1[2][7];
#pragma unroll
  for (int a = 0; a < 2; ++a)
#pragma unroll
    for (int b = 0; b < 7; ++b) { acc1[a][b][0] = 0.f; acc1[a][b][1] = 0.f; acc1[a][b][2] = 0.f; acc1[a][b][3] = 0.f; }
  gemm_layer<7, 12, AW1, true>(Ahi, Alo, wsp + L1F, wave * 7, lane, q, m, acc1);

  __syncthreads();  // all A reads done -> overlay h1 into same region
  _Float16* H1hi = Ahi;   // [32][416] swizzled
  _Float16* H1lo = Alo;
#pragma unroll
  for (int nt = 0; nt < 7; ++nt) {
    const int tile = wave * 7 + nt;
    if (tile < 26) {                 // only cols 0..415 needed for layer 2 K
      const int col = tile * 16 + m;
      const float bias = (col < 400) ? b1[col] : 0.f;
#pragma unroll
      for (int mt = 0; mt < 2; ++mt)
#pragma unroll
        for (int r = 0; r < 4; ++r) {
          const int row = mt * 16 + q * 4 + r;
          float v = fmaxf(acc1[mt][nt][r] + bias, 0.f);
          _Float16 hi = (_Float16)v;
          int off = (row * AW1 + col) * 2;
          off ^= (row & 7) << 4;
          *(_Float16*)((char*)H1hi + off) = hi;
          *(_Float16*)((char*)H1lo + off) = (_Float16)(v - (float)hi);
        }
    }
  }
  __syncthreads();

  // ================= Layer 2 =================
  floatx4 acc2[2][5];
#pragma unroll
  for (int a = 0; a < 2; ++a)
#pragma unroll
    for (int b = 0; b < 5; ++b) { acc2[a][b][0] = 0.f; acc2[a][b][1] = 0.f; acc2[a][b][2] = 0.f; acc2[a][b][3] = 0.f; }
  gemm_layer<5, 13, AW1, true>(H1hi, H1lo, wsp + L2F, wave * 5, lane, q, m, acc2);

  __syncthreads();  // all h1 reads done -> overlay h2 (padded, no swizzle)
  _Float16* H2hi = (_Float16*)smem;  // [32][328]
  _Float16* H2lo = H2hi + ROWS * AW2;
#pragma unroll
  for (int nt = 0; nt < 5; ++nt) {
    const int col = (wave * 5 + nt) * 16 + m;   // < 320; cols >=300 get zeros (padded W2/b2)
    const float bias = (col < 300) ? b2[col] : 0.f;
#pragma unroll
    for (int mt = 0; mt < 2; ++mt)
#pragma unroll
      for (int r = 0; r < 4; ++r) {
        const int row = mt * 16 + q * 4 + r;
        float v = fmaxf(acc2[mt][nt][r] + bias, 0.f);
        _Float16 hi = (_Float16)v;
        H2hi[row * AW2 + col] = hi;
        H2lo[row * AW2 + col] = (_Float16)(v - (float)hi);
      }
  }
  __syncthreads();

  // ================= Layer 3 =================
  floatx4 acc3[2][4];
#pragma unroll
  for (int a = 0; a < 2; ++a)
#pragma unroll
    for (int b = 0; b < 4; ++b) { acc3[a][b][0] = 0.f; acc3[a][b][1] = 0.f; acc3[a][b][2] = 0.f; acc3[a][b][3] = 0.f; }
  gemm_layer<4, 10, AW2, false>(H2hi, H2lo, wsp + L3F, wave * 4, lane, q, m, acc3);

  __syncthreads();  // all h2 reads done -> overlay O3
  float* O3 = (float*)smem;  // [32][260] fp32
#pragma unroll
  for (int nt = 0; nt < 4; ++nt) {
    const int col = (wave * 4 + nt) * 16 + m;
    const float bias = (col < 255) ? b3[col] : 0.f;
#pragma unroll
    for (int mt = 0; mt < 2; ++mt)
#pragma unroll
      for (int r = 0; r < 4; ++r) {
        const int row = mt * 16 + q * 4 + r;
        O3[row * OW3 + col] = tanhf(acc3[mt][nt][r] + bias);
      }
  }
  __syncthreads();

  // ================= Epilogue: mixture stats, sample, logprobs =================
  {
    const int row = t >> 3, p = t & 7;   // 8 threads per batch row
    const long gr = rowbase + row;
    const float* Or = O3 + row * OW3;
    float pc = 0.f, pt = 0.f, pe = 0.f;
    const int nact = (p == 0) ? 3 : 2;   // 17 = 8*2 + 1 (p==0 also covers a=16)
    for (int ia = 0; ia < nact; ++ia) {
      const int a = p + ia * 8;
      float mw[5], mmv[5], lms[5];
#pragma unroll
      for (int j = 0; j < 5; ++j) {
        mw[j]  = Or[a * 5 + j];
        mmv[j] = Or[85 + a * 5 + j];
        lms[j] = Or[170 + a * 5 + j];
      }
      float w[5], es = 0.f;
#pragma unroll
      for (int j = 0; j < 5; ++j) { w[j] = expf(mw[j]); es += w[j]; }
      const float inv = 1.f / es;
      float mean = 0.f;
#pragma unroll
      for (int j = 0; j < 5; ++j) { w[j] *= inv; mean += w[j] * mmv[j]; }
      float alea = 0.f, epis = 0.f;
#pragma unroll
      for (int j = 0; j < 5; ++j) {
        float sd = expf(fminf(fmaxf(lms[j], -10.f), 2.f));
        alea += w[j] * sd;
        float d = mmv[j] - mean;
        epis += w[j] * d * d;
      }
      epis = fminf(fmaxf(epis, 4.53999297624848e-05f), 7.38905609893065f);
      const float total = alea + epis;
      const float ea = eps[gr * NACT + a];
      const float sample = mean + total * ea;
      const float ts = tanhf(sample);
      out[gr * NACT + a] = ts;
      pc += logf(1.f - ts * ts + 1e-6f);
      const float dz = sample - mean;
      const float zt = dz / total;
      const float ze = dz / epis;
      pt += zt * zt + 2.f * logf(total);
      pe += ze * ze + 2.f * logf(epis);
    }
    pc += __shfl_xor(pc, 1); pc += __shfl_xor(pc, 2); pc += __shfl_xor(pc, 4);
    pt += __shfl_xor(pt, 1); pt += __shfl_xor(pt, 2); pt += __shfl_xor(pt, 4);
    pe += __shfl_xor(pe, 1); pe += __shfl_xor(pe, 2); pe += __shfl_xor(pe, 4);
    if (p == 0) {
      const float hdl2pi = 15.62195506447944f;  // 0.5*17*ln(2*pi)
      out[(long)NACT * BATCH + gr] = (-0.5f * pt - hdl2pi) - pc;
      out[(long)(NACT + 1) * BATCH + gr] = (-0.5f * pe - hdl2pi) - pc;
    }
  }
}

extern "C" void kernel_launch(void* const* d_in, const int* in_sizes, int n_in,
                              void* d_out, int out_size, void* d_ws, size_t ws_size,
                              hipStream_t stream) {
  const float* state = (const float*)d_in[0];
  const float* eps   = (const float*)d_in[1];
  const float* W1    = (const float*)d_in[2];
  const float* b1    = (const float*)d_in[3];
  const float* W2    = (const float*)d_in[4];
  const float* b2    = (const float*)d_in[5];
  const float* W3    = (const float*)d_in[6];
  const float* b3    = (const float*)d_in[7];
  float* out = (float*)d_out;
  _Float16* ws = (_Float16*)d_ws;

  (void)in_sizes; (void)n_in; (void)out_size; (void)ws_size;

  prep_kernel<<<(WTOTF + 255) / 256, 256, 0, stream>>>(W1, W2, W3, ws);
  actor_kernel<<<BATCH / ROWS, 256, LDS_BYTES, stream>>>(state, eps, b1, b2, b3, ws, out);
}